// Round 9
// baseline (3063.480 us; speedup 1.0000x reference)
//
#include <hip/hip_runtime.h>
#include <hip/hip_fp16.h>

// Problem constants
#define NH_   8
#define DQK_  256
#define DV_   64
#define NB_   8
#define TI_   16
#define TO_   16
#define HH_   32
#define WW_   32
#define FR_   (NB_*TI_)   // 128 frames
#define PX_   (HH_*WW_)   // 1024 pixels

typedef _Float16 f16x8 __attribute__((ext_vector_type(8)));
typedef _Float16 f16x4 __attribute__((ext_vector_type(4)));
typedef float    f32x4 __attribute__((ext_vector_type(4)));

// ---------------------------------------------------------------------------
// 1) v (fp32, [f][c][y][x]) -> v16t (f16, [f][y*32+x][c])
__global__ __launch_bounds__(256) void k_prep(const float* __restrict__ v,
                                              _Float16* __restrict__ v16t) {
    int blk = blockIdx.x;            // 512 blocks: f = blk>>2, quarter = blk&3
    int f = blk >> 2;
    int px = ((blk & 3) << 8) + threadIdx.x;
    const float* src = v + (size_t)f * DV_ * PX_;
    _Float16* dst = v16t + (size_t)f * PX_ * DV_ + (size_t)px * DV_;
    f16x8 buf[8];
    #pragma unroll
    for (int cg = 0; cg < 8; ++cg) {
        #pragma unroll
        for (int j = 0; j < 8; ++j)
            buf[cg][j] = (_Float16)src[(cg * 8 + j) * PX_ + px];
    }
    #pragma unroll
    for (int cg = 0; cg < 8; ++cg)
        *(f16x8*)(dst + cg * 8) = buf[cg];
}

// ---------------------------------------------------------------------------
// 2) pq = q@Wq + bq, pk = k@Wk + bk   (fp32, [row=b*16+t][2048])
__global__ void k_proj(const float* __restrict__ q, const float* __restrict__ kk,
                       const float* __restrict__ Wq, const float* __restrict__ bq,
                       const float* __restrict__ Wk, const float* __restrict__ bk,
                       float* __restrict__ pq, float* __restrict__ pk) {
    __shared__ float qs[32][256];
    int mat = blockIdx.z;
    const float* X  = mat ? kk : q;
    const float* Wm = mat ? Wk : Wq;
    const float* bm = mat ? bk : bq;
    float* out = mat ? pk : pq;
    int t = threadIdx.x;
    int by = blockIdx.y;              // 32-row block
    for (int idx = t; idx < 32 * 256; idx += 256) {
        int r = idx >> 8, k2 = idx & 255;
        qs[r][k2] = X[(by * 32 + r) * 256 + k2];
    }
    __syncthreads();
    int nd = blockIdx.x * 64 + (t & 63);
    int jb = (t >> 6) * 8;
    float a[8];
    #pragma unroll
    for (int j = 0; j < 8; ++j) a[j] = 0.f;
    #pragma unroll 8
    for (int k2 = 0; k2 < 256; ++k2) {
        float wv = Wm[k2 * 2048 + nd];
        #pragma unroll
        for (int j = 0; j < 8; ++j) a[j] += qs[jb + j][k2] * wv;
    }
    float bb = bm[nd];
    #pragma unroll
    for (int j = 0; j < 8; ++j)
        out[(size_t)(by * 32 + jb + j) * 2048 + nd] = a[j] + bb;
}

// ---------------------------------------------------------------------------
// 3) scores + mask + softmax -> wsm2[b][i][n*16+o]  fp32  (i-major layout so
//    k_comb can lane-distribute each i's 128 weights as one float2/lane)
__global__ void k_scores(const float* __restrict__ pq, const float* __restrict__ pk,
                         const int* __restrict__ mask, float* __restrict__ wsm2) {
    __shared__ float lq[16][256];
    __shared__ float lk[16][257];
    int b = blockIdx.x >> 3, n = blockIdx.x & 7;
    int t = threadIdx.x;
    for (int idx = t; idx < 4096; idx += 256) {
        int r = idx >> 8, dd = idx & 255;
        lq[r][dd] = pq[(size_t)(b * 16 + r) * 2048 + n * 256 + dd];
        lk[r][dd] = pk[(size_t)(b * 16 + r) * 2048 + n * 256 + dd];
    }
    __syncthreads();
    int o = t >> 4, i = t & 15;
    float s = 0.f;
    for (int dd = 0; dd < 256; ++dd) s += lq[o][dd] * lk[i][dd];
    s *= 0.0625f;  // 1/sqrt(256)
    if (mask[(b * 16 + o) * 16 + i] == 0) s = -1e10f;
    float mx = s;
    #pragma unroll
    for (int off = 1; off < 16; off <<= 1) mx = fmaxf(mx, __shfl_xor(mx, off, 16));
    float e = __expf(s - mx);
    float sum = e;
    #pragma unroll
    for (int off = 1; off < 16; off <<= 1) sum += __shfl_xor(sum, off, 16);
    wsm2[((size_t)(b * 16 + i) * 8 + n) * 16 + o] = e / sum;
}

// ---------------------------------------------------------------------------
// 4) Fold Wp into Wv -> Wf2 fragment layout:
//    gid = r*4096 + cg*2048 + oct16*64 + lane; oc = oct16*16+(lane&15),
//    c = cg*32+(lane>>4)*8+j;  Wf2[gid*8+j] = Wcomb[oc][c][r].
__global__ __launch_bounds__(256) void k_fold(const float* __restrict__ Wp,
                                              const float* __restrict__ Wv,
                                              _Float16* __restrict__ Wf2) {
    __shared__ float Wvs[64][64];   // [c'][c]
    __shared__ float Wps[64][65];   // [d][c'] — +1 pad
    int n = blockIdx.x & 7, r = blockIdx.x >> 3;   // grid 72
    int t = threadIdx.x;
    #pragma unroll
    for (int k = 0; k < 16; ++k) {
        int idx = t + 256 * k;
        int a2 = idx >> 6, bcol = idx & 63;
        Wvs[a2][bcol] = Wv[(size_t)(n * 64 + a2) * 576 + bcol * 9 + r];
        Wps[a2][bcol] = Wp[(size_t)a2 * 512 + n * 64 + bcol];
    }
    __syncthreads();
    int d = t & 63, cq = t >> 6;     // thread owns (d, 16 c's)
    float acc[2][8];
    #pragma unroll
    for (int jj = 0; jj < 2; ++jj)
        #pragma unroll
        for (int j = 0; j < 8; ++j) acc[jj][j] = 0.f;
    for (int c2 = 0; c2 < 64; ++c2) {
        float wp = Wps[d][c2];
        const float* row = &Wvs[c2][cq * 16];
        #pragma unroll
        for (int j = 0; j < 8; ++j) acc[0][j] += wp * row[j];
        #pragma unroll
        for (int j = 0; j < 8; ++j) acc[1][j] += wp * row[8 + j];
    }
    #pragma unroll
    for (int jj = 0; jj < 2; ++jj) {
        int cbase = cq * 16 + jj * 8;
        int cg = cbase >> 5;
        int lane = (d & 15) | (((cbase & 31) >> 3) << 4);
        int oct16 = n * 4 + (d >> 4);
        int gid = r * 4096 + cg * 2048 + oct16 * 64 + lane;
        f16x8 o8;
        #pragma unroll
        for (int j = 0; j < 8; ++j) o8[j] = (_Float16)acc[jj][j];
        *(f16x8*)&Wf2[(size_t)gid * 8] = o8;
    }
}

// bias_out[d] = bp[d] + sum_oc Wp[d][oc]*bv[oc]
__global__ void k_foldbias(const float* __restrict__ Wp, const float* __restrict__ bv,
                           const float* __restrict__ bp, float* __restrict__ bias_out) {
    int d = threadIdx.x;
    float acc = bp[d];
    for (int oc = 0; oc < 512; ++oc) acc += Wp[d * 512 + oc] * bv[oc];
    bias_out[d] = acc;
}

// ---------------------------------------------------------------------------
// 5) MFMA conv v4: 256 thr (4 waves, 2M x 2N). Block = 128 oc x 256 px.
//    Wave = 64 oc (4 m-frags) x 128 px (8 n-frags): per k-step 32 MFMA per
//    {4 A-loads + 8 B ds_reads}. vs v3: A-traffic HALVED (each A-byte feeds
//    8 n-frags; block 8 KB/step -> ~50 B/cyc per CU, under the ~60 B/cyc L2
//    budget) and A is REGISTER-DOUBLE-BUFFERED: step s+1's loads issue before
//    step s's MFMAs, hiding the ~200-300 cyc L2 latency that stalled v3
//    (201 us, MfmaUtil 15%). Slab 340x64 rows, proven zero-conflict swizzle.
__global__ __launch_bounds__(256, 2) void k_conv(const _Float16* __restrict__ v16t,
                                                 const _Float16* __restrict__ Wf2,
                                                 _Float16* __restrict__ g) {
    __shared__ _Float16 slab[340 * 64];  // 43520 B
    int f = blockIdx.z, ocb = blockIdx.y, pxb = blockIdx.x;
    int t = threadIdx.x;
    int l = t & 63, wv = t >> 6;
    int wmM = wv >> 1, wmN = wv & 1;     // 2M x 2N wave grid

    const _Float16* vb = v16t + (size_t)f * PX_ * DV_;
    int y0 = pxb * 8;
    for (int task = t; task < 340 * 8; task += 256) {
        int pos = task >> 3, sl = task & 7;
        int yy = pos / 34;
        int xx = pos - yy * 34;
        int y = y0 + yy - 1;
        int x = xx - 1;
        uint4 val = make_uint4(0u, 0u, 0u, 0u);
        if ((unsigned)y < 32u && (unsigned)x < 32u)
            val = *(const uint4*)(vb + (y * 32 + x) * 64 + sl * 8);
        int off = pos * 128 + ((sl ^ (pos & 7)) << 4);
        *(uint4*)((char*)slab + off) = val;
    }
    __syncthreads();

    int m = l & 15, kg = l >> 4;
    int pos0[8];
    #pragma unroll
    for (int nt = 0; nt < 8; ++nt) {
        int pxl = wmN * 128 + nt * 16 + m;         // 0..255 within block
        pos0[nt] = (pxl >> 5) * 34 + (pxl & 31);   // top-left sample (tap 0)
    }

    const f16x8* Wf8 = (const f16x8*)Wf2;
    f32x4 acc[4][8];
    #pragma unroll
    for (int mt = 0; mt < 4; ++mt)
        #pragma unroll
        for (int nt = 0; nt < 8; ++nt)
            acc[mt][nt] = (f32x4){0.f, 0.f, 0.f, 0.f};

    // A register double-buffer: load step s+1 while computing step s
    f16x8 afv[2][4];
    {
        int abase0 = ocb * 8 + wmM * 4;            // s=0: r=0, cg=0
        #pragma unroll
        for (int mt = 0; mt < 4; ++mt)
            afv[0][mt] = Wf8[(size_t)(abase0 + mt) * 64 + l];
    }

    #pragma unroll 6
    for (int s = 0; s < 18; ++s) {
        int cur = s & 1;
        if (s < 17) {
            int s1 = s + 1;
            int cg1 = s1 / 9, r1 = s1 - 9 * (s1 / 9);
            int abase1 = (r1 * 2 + cg1) * 32 + ocb * 8 + wmM * 4;
            #pragma unroll
            for (int mt = 0; mt < 4; ++mt)
                afv[cur ^ 1][mt] = Wf8[(size_t)(abase1 + mt) * 64 + l];
        }

        int cg = s / 9, r = s - 9 * (s / 9);
        int dd = (r / 3) * 34 + (r % 3);
        int slotb = (cg * 4 + kg) << 4;

        f16x8 bfv[8];
        #pragma unroll
        for (int nt = 0; nt < 8; ++nt) {
            int pos = pos0[nt] + dd;
            int off = pos * 128 + (slotb ^ ((pos & 7) << 4));
            bfv[nt] = *(const f16x8*)((const char*)slab + off);
        }

        #pragma unroll
        for (int mt = 0; mt < 4; ++mt)
            #pragma unroll
            for (int nt = 0; nt < 8; ++nt)
                acc[mt][nt] = __builtin_amdgcn_mfma_f32_16x16x32_f16(afv[cur][mt], bfv[nt], acc[mt][nt], 0, 0, 0);
    }

    // epilogue: g[f][oc][px], C frag: row=oc=(kg*4+e), col=px=(m)
    _Float16* gb = g + (size_t)f * 512 * 1024;
    #pragma unroll
    for (int mt = 0; mt < 4; ++mt) {
        int oc0 = (ocb * 8 + wmM * 4 + mt) * 16 + kg * 4;
        #pragma unroll
        for (int nt = 0; nt < 8; ++nt) {
            int px = pxb * 256 + wmN * 128 + nt * 16 + m;
            #pragma unroll
            for (int e = 0; e < 4; ++e)
                gb[(size_t)(oc0 + e) * 1024 + px] = (_Float16)acc[mt][nt][e];
        }
    }
}

// ---------------------------------------------------------------------------
// 6) combine: out[b,o,d,px] = bias[d] + sum_{n,i} w[b,i,n,o] * g[b,i,n*64+d,px]
//    w path: per i, lanes cooperatively load 128 weights (float2/lane), then
//    compile-time __builtin_amdgcn_readlane -> SGPR operand FMAs.
__global__ __launch_bounds__(256) void k_comb(const _Float16* __restrict__ g,
                                              const float* __restrict__ wsm2,
                                              const float* __restrict__ bias_out,
                                              float* __restrict__ out) {
    int d = blockIdx.y, b = blockIdx.z;
    int t = threadIdx.x;
    int px0 = t * 4;
    float acc[16][4];
    #pragma unroll
    for (int o = 0; o < 16; ++o)
        #pragma unroll
        for (int e = 0; e < 4; ++e) acc[o][e] = 0.f;

    for (int i = 0; i < 16; ++i) {
        // lane l holds w[idx=2l], w[idx=2l+1] where idx = n*16+o
        float2 wv = *(const float2*)&wsm2[(size_t)(b * 16 + i) * 128 + 2 * (t & 63)];
        #pragma unroll
        for (int n = 0; n < 8; ++n) {
            const _Float16* gp = g + ((size_t)((b * 16 + i) * 512 + n * 64 + d)) * 1024 + px0;
            f16x4 hv = *(const f16x4*)gp;
            float g0 = (float)hv[0], g1 = (float)hv[1], g2 = (float)hv[2], g3 = (float)hv[3];
            #pragma unroll
            for (int o = 0; o < 16; ++o) {
                int idx = n * 16 + o;
                int src = (idx & 1) ? __float_as_int(wv.y) : __float_as_int(wv.x);
                float w = __int_as_float(__builtin_amdgcn_readlane(src, idx >> 1));
                acc[o][0] += w * g0;
                acc[o][1] += w * g1;
                acc[o][2] += w * g2;
                acc[o][3] += w * g3;
            }
        }
    }
    float bo = bias_out[d];
    #pragma unroll
    for (int o = 0; o < 16; ++o) {
        float4 res = make_float4(acc[o][0] + bo, acc[o][1] + bo, acc[o][2] + bo, acc[o][3] + bo);
        *(float4*)(out + ((size_t)((b * 16 + o) * 64 + d)) * 1024 + px0) = res;
    }
}

// ---------------------------------------------------------------------------
extern "C" void kernel_launch(void* const* d_in, const int* in_sizes, int n_in,
                              void* d_out, int out_size, void* d_ws, size_t ws_size,
                              hipStream_t stream) {
    (void)in_sizes; (void)n_in; (void)out_size;
    const float* v  = (const float*)d_in[0];
    const float* kk = (const float*)d_in[1];
    const float* q  = (const float*)d_in[2];
    const int*   pm = (const int*)d_in[3];
    const float* Wq = (const float*)d_in[4];
    const float* bq = (const float*)d_in[5];
    const float* Wk = (const float*)d_in[6];
    const float* bk = (const float*)d_in[7];
    const float* Wv = (const float*)d_in[8];
    const float* bv = (const float*)d_in[9];
    const float* Wp = (const float*)d_in[10];
    const float* bp = (const float*)d_in[11];
    float* out = (float*)d_out;

    char* ws = (char*)d_ws;
    size_t o_v16t = 0;
    size_t o_g    = o_v16t + (size_t)FR_ * PX_ * DV_ * 2;          // 16 MB
    size_t o_wf2  = o_g    + (size_t)FR_ * 512 * PX_ * 2;          // +128 MB
    size_t o_pq   = o_wf2  + (size_t)9 * 2 * 32 * 64 * 8 * 2;      // +576 KB
    size_t o_pk   = o_pq   + (size_t)128 * 2048 * 4;               // +1 MB
    size_t o_wsm  = o_pk   + (size_t)128 * 2048 * 4;               // +1 MB
    size_t o_bias = o_wsm  + (size_t)NB_ * NH_ * TO_ * TI_ * 4;    // +64 KB
    size_t need   = o_bias + 256;
    if (ws_size < need) return;  // insufficient workspace; validation will flag

    _Float16* v16t = (_Float16*)(ws + o_v16t);
    _Float16* g    = (_Float16*)(ws + o_g);
    _Float16* Wf2  = (_Float16*)(ws + o_wf2);
    float* pq      = (float*)(ws + o_pq);
    float* pk      = (float*)(ws + o_pk);
    float* wsm2    = (float*)(ws + o_wsm);
    float* bias    = (float*)(ws + o_bias);

    k_prep<<<dim3(512), dim3(256), 0, stream>>>(v, v16t);
    k_proj<<<dim3(32, 4, 2), dim3(256), 0, stream>>>(q, kk, Wq, bq, Wk, bk, pq, pk);
    k_scores<<<dim3(64), dim3(256), 0, stream>>>(pq, pk, pm, wsm2);
    k_fold<<<dim3(72), dim3(256), 0, stream>>>(Wp, Wv, Wf2);
    k_foldbias<<<dim3(1), dim3(64), 0, stream>>>(Wp, bv, bp, bias);
    k_conv<<<dim3(4, 4, FR_), dim3(256), 0, stream>>>(v16t, Wf2, g);
    k_comb<<<dim3(1, 64, NB_), dim3(256), 0, stream>>>(g, wsm2, bias, out);
}

// Round 10
// 421.295 us; speedup vs baseline: 7.2716x; 7.2716x over previous
//
#include <hip/hip_runtime.h>
#include <hip/hip_fp16.h>

// Problem constants
#define NH_   8
#define DQK_  256
#define DV_   64
#define NB_   8
#define TI_   16
#define TO_   16
#define HH_   32
#define WW_   32
#define FR_   (NB_*TI_)   // 128 frames
#define PX_   (HH_*WW_)   // 1024 pixels

typedef _Float16 f16x8 __attribute__((ext_vector_type(8)));
typedef _Float16 f16x4 __attribute__((ext_vector_type(4)));
typedef float    f32x4 __attribute__((ext_vector_type(4)));

// ---------------------------------------------------------------------------
// 1) v (fp32, [f][c][y][x]) -> v16t (f16, [f][y*32+x][c])
__global__ __launch_bounds__(256) void k_prep(const float* __restrict__ v,
                                              _Float16* __restrict__ v16t) {
    int blk = blockIdx.x;            // 512 blocks: f = blk>>2, quarter = blk&3
    int f = blk >> 2;
    int px = ((blk & 3) << 8) + threadIdx.x;
    const float* src = v + (size_t)f * DV_ * PX_;
    _Float16* dst = v16t + (size_t)f * PX_ * DV_ + (size_t)px * DV_;
    f16x8 buf[8];
    #pragma unroll
    for (int cg = 0; cg < 8; ++cg) {
        #pragma unroll
        for (int j = 0; j < 8; ++j)
            buf[cg][j] = (_Float16)src[(cg * 8 + j) * PX_ + px];
    }
    #pragma unroll
    for (int cg = 0; cg < 8; ++cg)
        *(f16x8*)(dst + cg * 8) = buf[cg];
}

// ---------------------------------------------------------------------------
// 2) pq = q@Wq + bq, pk = k@Wk + bk   (fp32, [row=b*16+t][2048])
__global__ void k_proj(const float* __restrict__ q, const float* __restrict__ kk,
                       const float* __restrict__ Wq, const float* __restrict__ bq,
                       const float* __restrict__ Wk, const float* __restrict__ bk,
                       float* __restrict__ pq, float* __restrict__ pk) {
    __shared__ float qs[32][256];
    int mat = blockIdx.z;
    const float* X  = mat ? kk : q;
    const float* Wm = mat ? Wk : Wq;
    const float* bm = mat ? bk : bq;
    float* out = mat ? pk : pq;
    int t = threadIdx.x;
    int by = blockIdx.y;              // 32-row block
    for (int idx = t; idx < 32 * 256; idx += 256) {
        int r = idx >> 8, k2 = idx & 255;
        qs[r][k2] = X[(by * 32 + r) * 256 + k2];
    }
    __syncthreads();
    int nd = blockIdx.x * 64 + (t & 63);
    int jb = (t >> 6) * 8;
    float a[8];
    #pragma unroll
    for (int j = 0; j < 8; ++j) a[j] = 0.f;
    #pragma unroll 8
    for (int k2 = 0; k2 < 256; ++k2) {
        float wv = Wm[k2 * 2048 + nd];
        #pragma unroll
        for (int j = 0; j < 8; ++j) a[j] += qs[jb + j][k2] * wv;
    }
    float bb = bm[nd];
    #pragma unroll
    for (int j = 0; j < 8; ++j)
        out[(size_t)(by * 32 + jb + j) * 2048 + nd] = a[j] + bb;
}

// ---------------------------------------------------------------------------
// 3) scores + mask + softmax -> wsm2[b][i][n*16+o]  fp32  (i-major layout so
//    k_comb can lane-distribute each i's 128 weights as one float2/lane)
__global__ void k_scores(const float* __restrict__ pq, const float* __restrict__ pk,
                         const int* __restrict__ mask, float* __restrict__ wsm2) {
    __shared__ float lq[16][256];
    __shared__ float lk[16][257];
    int b = blockIdx.x >> 3, n = blockIdx.x & 7;
    int t = threadIdx.x;
    for (int idx = t; idx < 4096; idx += 256) {
        int r = idx >> 8, dd = idx & 255;
        lq[r][dd] = pq[(size_t)(b * 16 + r) * 2048 + n * 256 + dd];
        lk[r][dd] = pk[(size_t)(b * 16 + r) * 2048 + n * 256 + dd];
    }
    __syncthreads();
    int o = t >> 4, i = t & 15;
    float s = 0.f;
    for (int dd = 0; dd < 256; ++dd) s += lq[o][dd] * lk[i][dd];
    s *= 0.0625f;  // 1/sqrt(256)
    if (mask[(b * 16 + o) * 16 + i] == 0) s = -1e10f;
    float mx = s;
    #pragma unroll
    for (int off = 1; off < 16; off <<= 1) mx = fmaxf(mx, __shfl_xor(mx, off, 16));
    float e = __expf(s - mx);
    float sum = e;
    #pragma unroll
    for (int off = 1; off < 16; off <<= 1) sum += __shfl_xor(sum, off, 16);
    wsm2[((size_t)(b * 16 + i) * 8 + n) * 16 + o] = e / sum;
}

// ---------------------------------------------------------------------------
// 4) Fold Wp into Wv -> Wf2 fragment layout:
//    gid = r*4096 + cg*2048 + oct16*64 + lane; oc = oct16*16+(lane&15),
//    c = cg*32+(lane>>4)*8+j;  Wf2[gid*8+j] = Wcomb[oc][c][r].
__global__ __launch_bounds__(256) void k_fold(const float* __restrict__ Wp,
                                              const float* __restrict__ Wv,
                                              _Float16* __restrict__ Wf2) {
    __shared__ float Wvs[64][64];   // [c'][c]
    __shared__ float Wps[64][65];   // [d][c'] — +1 pad
    int n = blockIdx.x & 7, r = blockIdx.x >> 3;   // grid 72
    int t = threadIdx.x;
    #pragma unroll
    for (int k = 0; k < 16; ++k) {
        int idx = t + 256 * k;
        int a2 = idx >> 6, bcol = idx & 63;
        Wvs[a2][bcol] = Wv[(size_t)(n * 64 + a2) * 576 + bcol * 9 + r];
        Wps[a2][bcol] = Wp[(size_t)a2 * 512 + n * 64 + bcol];
    }
    __syncthreads();
    int d = t & 63, cq = t >> 6;     // thread owns (d, 16 c's)
    float acc[2][8];
    #pragma unroll
    for (int jj = 0; jj < 2; ++jj)
        #pragma unroll
        for (int j = 0; j < 8; ++j) acc[jj][j] = 0.f;
    for (int c2 = 0; c2 < 64; ++c2) {
        float wp = Wps[d][c2];
        const float* row = &Wvs[c2][cq * 16];
        #pragma unroll
        for (int j = 0; j < 8; ++j) acc[0][j] += wp * row[j];
        #pragma unroll
        for (int j = 0; j < 8; ++j) acc[1][j] += wp * row[8 + j];
    }
    #pragma unroll
    for (int jj = 0; jj < 2; ++jj) {
        int cbase = cq * 16 + jj * 8;
        int cg = cbase >> 5;
        int lane = (d & 15) | (((cbase & 31) >> 3) << 4);
        int oct16 = n * 4 + (d >> 4);
        int gid = r * 4096 + cg * 2048 + oct16 * 64 + lane;
        f16x8 o8;
        #pragma unroll
        for (int j = 0; j < 8; ++j) o8[j] = (_Float16)acc[jj][j];
        *(f16x8*)&Wf2[(size_t)gid * 8] = o8;
    }
}

// bias_out[d] = bp[d] + sum_oc Wp[d][oc]*bv[oc]
__global__ void k_foldbias(const float* __restrict__ Wp, const float* __restrict__ bv,
                           const float* __restrict__ bp, float* __restrict__ bias_out) {
    int d = threadIdx.x;
    float acc = bp[d];
    for (int oc = 0; oc < 512; ++oc) acc += Wp[d * 512 + oc] * bv[oc];
    bias_out[d] = acc;
}

// ---------------------------------------------------------------------------
// 5) MFMA conv v5: v4's tiling (4 waves 2Mx2N; wave = 64 oc x 128 px;
//    32 MFMA per {4 A-loads + 8 B ds_reads}) but the A double-buffer is
//    fully STATIC (named afvA/afvB, 9x two-step fully-unrolled body, every
//    index compile-time). v4 indexed afv[s&1] with runtime s under partial
//    unroll -> dynamic register indexing -> v_movrel/scratch lowering
//    (rule #20): MfmaUtil 1%, VALUBusy 35%, VGPR_Count an impossible 124.
__global__ __launch_bounds__(256, 2) void k_conv(const _Float16* __restrict__ v16t,
                                                 const _Float16* __restrict__ Wf2,
                                                 _Float16* __restrict__ g) {
    __shared__ _Float16 slab[340 * 64];  // 43520 B
    int f = blockIdx.z, ocb = blockIdx.y, pxb = blockIdx.x;
    int t = threadIdx.x;
    int l = t & 63, wv = t >> 6;
    int wmM = wv >> 1, wmN = wv & 1;     // 2M x 2N wave grid

    const _Float16* vb = v16t + (size_t)f * PX_ * DV_;
    int y0 = pxb * 8;
    for (int task = t; task < 340 * 8; task += 256) {
        int pos = task >> 3, sl = task & 7;
        int yy = pos / 34;
        int xx = pos - yy * 34;
        int y = y0 + yy - 1;
        int x = xx - 1;
        uint4 val = make_uint4(0u, 0u, 0u, 0u);
        if ((unsigned)y < 32u && (unsigned)x < 32u)
            val = *(const uint4*)(vb + (y * 32 + x) * 64 + sl * 8);
        int off = pos * 128 + ((sl ^ (pos & 7)) << 4);
        *(uint4*)((char*)slab + off) = val;
    }
    __syncthreads();

    int m = l & 15, kg = l >> 4;
    int pos0[8];
    #pragma unroll
    for (int nt = 0; nt < 8; ++nt) {
        int pxl = wmN * 128 + nt * 16 + m;         // 0..255 within block
        pos0[nt] = (pxl >> 5) * 34 + (pxl & 31);   // top-left sample (tap 0)
    }

    const f16x8* Wf8 = (const f16x8*)Wf2;
    f32x4 acc[4][8];
    #pragma unroll
    for (int mt = 0; mt < 4; ++mt)
        #pragma unroll
        for (int nt = 0; nt < 8; ++nt)
            acc[mt][nt] = (f32x4){0.f, 0.f, 0.f, 0.f};

    f16x8 afvA[4], afvB[4];

#define APRELOAD(buf, ss) do {                                              \
    int cg_ = (ss) / 9, r_ = (ss) % 9;                                      \
    int ab_ = (r_ * 2 + cg_) * 32 + ocb * 8 + wmM * 4;                      \
    _Pragma("unroll")                                                       \
    for (int mt = 0; mt < 4; ++mt)                                          \
        buf[mt] = Wf8[(size_t)(ab_ + mt) * 64 + l];                         \
} while (0)

#define ASTEP(buf, ss) do {                                                 \
    int cg_ = (ss) / 9, r_ = (ss) % 9;                                      \
    int dd_ = (r_ / 3) * 34 + (r_ % 3);                                     \
    int slotb_ = (cg_ * 4 + kg) << 4;                                       \
    f16x8 bfv[8];                                                           \
    _Pragma("unroll")                                                       \
    for (int nt = 0; nt < 8; ++nt) {                                        \
        int pos_ = pos0[nt] + dd_;                                          \
        int off_ = pos_ * 128 + (slotb_ ^ ((pos_ & 7) << 4));               \
        bfv[nt] = *(const f16x8*)((const char*)slab + off_);                \
    }                                                                       \
    _Pragma("unroll")                                                       \
    for (int mt = 0; mt < 4; ++mt)                                          \
        _Pragma("unroll")                                                   \
        for (int nt = 0; nt < 8; ++nt)                                      \
            acc[mt][nt] = __builtin_amdgcn_mfma_f32_16x16x32_f16(           \
                buf[mt], bfv[nt], acc[mt][nt], 0, 0, 0);                    \
} while (0)

    APRELOAD(afvA, 0);
    #pragma unroll
    for (int sp = 0; sp < 9; ++sp) {
        APRELOAD(afvB, 2 * sp + 1);       // prefetch odd step
        ASTEP(afvA, 2 * sp);              // compute even step
        if (sp < 8) APRELOAD(afvA, 2 * sp + 2);  // prefetch next even step
        ASTEP(afvB, 2 * sp + 1);          // compute odd step
    }
#undef APRELOAD
#undef ASTEP

    // epilogue: g[f][oc][px], C frag: row=oc=(kg*4+e), col=px=(m)
    _Float16* gb = g + (size_t)f * 512 * 1024;
    #pragma unroll
    for (int mt = 0; mt < 4; ++mt) {
        int oc0 = (ocb * 8 + wmM * 4 + mt) * 16 + kg * 4;
        #pragma unroll
        for (int nt = 0; nt < 8; ++nt) {
            int px = pxb * 256 + wmN * 128 + nt * 16 + m;
            #pragma unroll
            for (int e = 0; e < 4; ++e)
                gb[(size_t)(oc0 + e) * 1024 + px] = (_Float16)acc[mt][nt][e];
        }
    }
}

// ---------------------------------------------------------------------------
// 6) combine: out[b,o,d,px] = bias[d] + sum_{n,i} w[b,i,n,o] * g[b,i,n*64+d,px]
//    w path: per i, lanes cooperatively load 128 weights (float2/lane), then
//    compile-time __builtin_amdgcn_readlane -> SGPR operand FMAs.
__global__ __launch_bounds__(256) void k_comb(const _Float16* __restrict__ g,
                                              const float* __restrict__ wsm2,
                                              const float* __restrict__ bias_out,
                                              float* __restrict__ out) {
    int d = blockIdx.y, b = blockIdx.z;
    int t = threadIdx.x;
    int px0 = t * 4;
    float acc[16][4];
    #pragma unroll
    for (int o = 0; o < 16; ++o)
        #pragma unroll
        for (int e = 0; e < 4; ++e) acc[o][e] = 0.f;

    for (int i = 0; i < 16; ++i) {
        // lane l holds w[idx=2l], w[idx=2l+1] where idx = n*16+o
        float2 wv = *(const float2*)&wsm2[(size_t)(b * 16 + i) * 128 + 2 * (t & 63)];
        #pragma unroll
        for (int n = 0; n < 8; ++n) {
            const _Float16* gp = g + ((size_t)((b * 16 + i) * 512 + n * 64 + d)) * 1024 + px0;
            f16x4 hv = *(const f16x4*)gp;
            float g0 = (float)hv[0], g1 = (float)hv[1], g2 = (float)hv[2], g3 = (float)hv[3];
            #pragma unroll
            for (int o = 0; o < 16; ++o) {
                int idx = n * 16 + o;
                int src = (idx & 1) ? __float_as_int(wv.y) : __float_as_int(wv.x);
                float w = __int_as_float(__builtin_amdgcn_readlane(src, idx >> 1));
                acc[o][0] += w * g0;
                acc[o][1] += w * g1;
                acc[o][2] += w * g2;
                acc[o][3] += w * g3;
            }
        }
    }
    float bo = bias_out[d];
    #pragma unroll
    for (int o = 0; o < 16; ++o) {
        float4 res = make_float4(acc[o][0] + bo, acc[o][1] + bo, acc[o][2] + bo, acc[o][3] + bo);
        *(float4*)(out + ((size_t)((b * 16 + o) * 64 + d)) * 1024 + px0) = res;
    }
}

// ---------------------------------------------------------------------------
extern "C" void kernel_launch(void* const* d_in, const int* in_sizes, int n_in,
                              void* d_out, int out_size, void* d_ws, size_t ws_size,
                              hipStream_t stream) {
    (void)in_sizes; (void)n_in; (void)out_size;
    const float* v  = (const float*)d_in[0];
    const float* kk = (const float*)d_in[1];
    const float* q  = (const float*)d_in[2];
    const int*   pm = (const int*)d_in[3];
    const float* Wq = (const float*)d_in[4];
    const float* bq = (const float*)d_in[5];
    const float* Wk = (const float*)d_in[6];
    const float* bk = (const float*)d_in[7];
    const float* Wv = (const float*)d_in[8];
    const float* bv = (const float*)d_in[9];
    const float* Wp = (const float*)d_in[10];
    const float* bp = (const float*)d_in[11];
    float* out = (float*)d_out;

    char* ws = (char*)d_ws;
    size_t o_v16t = 0;
    size_t o_g    = o_v16t + (size_t)FR_ * PX_ * DV_ * 2;          // 16 MB
    size_t o_wf2  = o_g    + (size_t)FR_ * 512 * PX_ * 2;          // +128 MB
    size_t o_pq   = o_wf2  + (size_t)9 * 2 * 32 * 64 * 8 * 2;      // +576 KB
    size_t o_pk   = o_pq   + (size_t)128 * 2048 * 4;               // +1 MB
    size_t o_wsm  = o_pk   + (size_t)128 * 2048 * 4;               // +1 MB
    size_t o_bias = o_wsm  + (size_t)NB_ * NH_ * TO_ * TI_ * 4;    // +64 KB
    size_t need   = o_bias + 256;
    if (ws_size < need) return;  // insufficient workspace; validation will flag

    _Float16* v16t = (_Float16*)(ws + o_v16t);
    _Float16* g    = (_Float16*)(ws + o_g);
    _Float16* Wf2  = (_Float16*)(ws + o_wf2);
    float* pq      = (float*)(ws + o_pq);
    float* pk      = (float*)(ws + o_pk);
    float* wsm2    = (float*)(ws + o_wsm);
    float* bias    = (float*)(ws + o_bias);

    k_prep<<<dim3(512), dim3(256), 0, stream>>>(v, v16t);
    k_proj<<<dim3(32, 4, 2), dim3(256), 0, stream>>>(q, kk, Wq, bq, Wk, bk, pq, pk);
    k_scores<<<dim3(64), dim3(256), 0, stream>>>(pq, pk, pm, wsm2);
    k_fold<<<dim3(72), dim3(256), 0, stream>>>(Wp, Wv, Wf2);
    k_foldbias<<<dim3(1), dim3(64), 0, stream>>>(Wp, bv, bp, bias);
    k_conv<<<dim3(4, 4, FR_), dim3(256), 0, stream>>>(v16t, Wf2, g);
    k_comb<<<dim3(1, 64, NB_), dim3(256), 0, stream>>>(g, wsm2, bias, out);
}

// Round 11
// 410.580 us; speedup vs baseline: 7.4614x; 1.0261x over previous
//
#include <hip/hip_runtime.h>
#include <hip/hip_fp16.h>

// Problem constants
#define NH_   8
#define DQK_  256
#define DV_   64
#define NB_   8
#define TI_   16
#define TO_   16
#define HH_   32
#define WW_   32
#define FR_   (NB_*TI_)   // 128 frames
#define PX_   (HH_*WW_)   // 1024 pixels

typedef _Float16 f16x8 __attribute__((ext_vector_type(8)));
typedef _Float16 f16x4 __attribute__((ext_vector_type(4)));
typedef float    f32x4 __attribute__((ext_vector_type(4)));

// ---------------------------------------------------------------------------
// 1) v (fp32, [f][c][y][x]) -> v16t (f16, [f][y*32+x][c])
__global__ __launch_bounds__(256) void k_prep(const float* __restrict__ v,
                                              _Float16* __restrict__ v16t) {
    int blk = blockIdx.x;            // 512 blocks: f = blk>>2, quarter = blk&3
    int f = blk >> 2;
    int px = ((blk & 3) << 8) + threadIdx.x;
    const float* src = v + (size_t)f * DV_ * PX_;
    _Float16* dst = v16t + (size_t)f * PX_ * DV_ + (size_t)px * DV_;
    f16x8 buf[8];
    #pragma unroll
    for (int cg = 0; cg < 8; ++cg) {
        #pragma unroll
        for (int j = 0; j < 8; ++j)
            buf[cg][j] = (_Float16)src[(cg * 8 + j) * PX_ + px];
    }
    #pragma unroll
    for (int cg = 0; cg < 8; ++cg)
        *(f16x8*)(dst + cg * 8) = buf[cg];
}

// ---------------------------------------------------------------------------
// 2) pq = q@Wq + bq, pk = k@Wk + bk   (fp32, [row=b*16+t][2048])
__global__ void k_proj(const float* __restrict__ q, const float* __restrict__ kk,
                       const float* __restrict__ Wq, const float* __restrict__ bq,
                       const float* __restrict__ Wk, const float* __restrict__ bk,
                       float* __restrict__ pq, float* __restrict__ pk) {
    __shared__ float qs[32][256];
    int mat = blockIdx.z;
    const float* X  = mat ? kk : q;
    const float* Wm = mat ? Wk : Wq;
    const float* bm = mat ? bk : bq;
    float* out = mat ? pk : pq;
    int t = threadIdx.x;
    int by = blockIdx.y;              // 32-row block
    for (int idx = t; idx < 32 * 256; idx += 256) {
        int r = idx >> 8, k2 = idx & 255;
        qs[r][k2] = X[(by * 32 + r) * 256 + k2];
    }
    __syncthreads();
    int nd = blockIdx.x * 64 + (t & 63);
    int jb = (t >> 6) * 8;
    float a[8];
    #pragma unroll
    for (int j = 0; j < 8; ++j) a[j] = 0.f;
    #pragma unroll 8
    for (int k2 = 0; k2 < 256; ++k2) {
        float wv = Wm[k2 * 2048 + nd];
        #pragma unroll
        for (int j = 0; j < 8; ++j) a[j] += qs[jb + j][k2] * wv;
    }
    float bb = bm[nd];
    #pragma unroll
    for (int j = 0; j < 8; ++j)
        out[(size_t)(by * 32 + jb + j) * 2048 + nd] = a[j] + bb;
}

// ---------------------------------------------------------------------------
// 3) scores + mask + softmax -> wsm2[b][i][n*16+o]  fp32  (i-major layout so
//    k_comb can lane-distribute each i's 128 weights as one float2/lane)
__global__ void k_scores(const float* __restrict__ pq, const float* __restrict__ pk,
                         const int* __restrict__ mask, float* __restrict__ wsm2) {
    __shared__ float lq[16][256];
    __shared__ float lk[16][257];
    int b = blockIdx.x >> 3, n = blockIdx.x & 7;
    int t = threadIdx.x;
    for (int idx = t; idx < 4096; idx += 256) {
        int r = idx >> 8, dd = idx & 255;
        lq[r][dd] = pq[(size_t)(b * 16 + r) * 2048 + n * 256 + dd];
        lk[r][dd] = pk[(size_t)(b * 16 + r) * 2048 + n * 256 + dd];
    }
    __syncthreads();
    int o = t >> 4, i = t & 15;
    float s = 0.f;
    for (int dd = 0; dd < 256; ++dd) s += lq[o][dd] * lk[i][dd];
    s *= 0.0625f;  // 1/sqrt(256)
    if (mask[(b * 16 + o) * 16 + i] == 0) s = -1e10f;
    float mx = s;
    #pragma unroll
    for (int off = 1; off < 16; off <<= 1) mx = fmaxf(mx, __shfl_xor(mx, off, 16));
    float e = __expf(s - mx);
    float sum = e;
    #pragma unroll
    for (int off = 1; off < 16; off <<= 1) sum += __shfl_xor(sum, off, 16);
    wsm2[((size_t)(b * 16 + i) * 8 + n) * 16 + o] = e / sum;
}

// ---------------------------------------------------------------------------
// 4) Fold Wp into Wv -> Wf2 fragment layout:
//    gid = r*4096 + cg*2048 + oct16*64 + lane; oc = oct16*16+(lane&15),
//    c = cg*32+(lane>>4)*8+j;  Wf2[gid*8+j] = Wcomb[oc][c][r].
__global__ __launch_bounds__(256) void k_fold(const float* __restrict__ Wp,
                                              const float* __restrict__ Wv,
                                              _Float16* __restrict__ Wf2) {
    __shared__ float Wvs[64][64];   // [c'][c]
    __shared__ float Wps[64][65];   // [d][c'] — +1 pad
    int n = blockIdx.x & 7, r = blockIdx.x >> 3;   // grid 72
    int t = threadIdx.x;
    #pragma unroll
    for (int k = 0; k < 16; ++k) {
        int idx = t + 256 * k;
        int a2 = idx >> 6, bcol = idx & 63;
        Wvs[a2][bcol] = Wv[(size_t)(n * 64 + a2) * 576 + bcol * 9 + r];
        Wps[a2][bcol] = Wp[(size_t)a2 * 512 + n * 64 + bcol];
    }
    __syncthreads();
    int d = t & 63, cq = t >> 6;     // thread owns (d, 16 c's)
    float acc[2][8];
    #pragma unroll
    for (int jj = 0; jj < 2; ++jj)
        #pragma unroll
        for (int j = 0; j < 8; ++j) acc[jj][j] = 0.f;
    for (int c2 = 0; c2 < 64; ++c2) {
        float wp = Wps[d][c2];
        const float* row = &Wvs[c2][cq * 16];
        #pragma unroll
        for (int j = 0; j < 8; ++j) acc[0][j] += wp * row[j];
        #pragma unroll
        for (int j = 0; j < 8; ++j) acc[1][j] += wp * row[8 + j];
    }
    #pragma unroll
    for (int jj = 0; jj < 2; ++jj) {
        int cbase = cq * 16 + jj * 8;
        int cg = cbase >> 5;
        int lane = (d & 15) | (((cbase & 31) >> 3) << 4);
        int oct16 = n * 4 + (d >> 4);
        int gid = r * 4096 + cg * 2048 + oct16 * 64 + lane;
        f16x8 o8;
        #pragma unroll
        for (int j = 0; j < 8; ++j) o8[j] = (_Float16)acc[jj][j];
        *(f16x8*)&Wf2[(size_t)gid * 8] = o8;
    }
}

// bias_out[d] = bp[d] + sum_oc Wp[d][oc]*bv[oc]
__global__ void k_foldbias(const float* __restrict__ Wp, const float* __restrict__ bv,
                           const float* __restrict__ bp, float* __restrict__ bias_out) {
    int d = threadIdx.x;
    float acc = bp[d];
    for (int oc = 0; oc < 512; ++oc) acc += Wp[d * 512 + oc] * bv[oc];
    bias_out[d] = acc;
}

// ---------------------------------------------------------------------------
// 5) MFMA conv v6: v5's tiling (4 waves 2Mx2N; wave = 64 oc x 128 px;
//    32 MFMA per {4 A-loads + 8 B ds_reads}) with the REGISTER FOOTPRINT cut
//    to fit 256/wave (v5 spilled ~280 MB scratch: FETCH 115 MB, WRITE 317 MB,
//    VGPR_Count=128 = arch half of the 256 cap, acc[4][8]=128 AGPR):
//    - single afv buffer per step (no explicit dbuf; the co-resident wave's
//      MFMAs cover A's L2 latency, m114)
//    - B interleaved per nt: {ds_read bfv; 4 MFMAs} -> 1-2 live bfv, not 8.
//    Arch VGPR ~70-80 + 128 AGPR => fits, no scratch.
__global__ __launch_bounds__(256, 2) void k_conv(const _Float16* __restrict__ v16t,
                                                 const _Float16* __restrict__ Wf2,
                                                 _Float16* __restrict__ g) {
    __shared__ _Float16 slab[340 * 64];  // 43520 B
    int f = blockIdx.z, ocb = blockIdx.y, pxb = blockIdx.x;
    int t = threadIdx.x;
    int l = t & 63, wv = t >> 6;
    int wmM = wv >> 1, wmN = wv & 1;     // 2M x 2N wave grid

    const _Float16* vb = v16t + (size_t)f * PX_ * DV_;
    int y0 = pxb * 8;
    for (int task = t; task < 340 * 8; task += 256) {
        int pos = task >> 3, sl = task & 7;
        int yy = pos / 34;
        int xx = pos - yy * 34;
        int y = y0 + yy - 1;
        int x = xx - 1;
        uint4 val = make_uint4(0u, 0u, 0u, 0u);
        if ((unsigned)y < 32u && (unsigned)x < 32u)
            val = *(const uint4*)(vb + (y * 32 + x) * 64 + sl * 8);
        int off = pos * 128 + ((sl ^ (pos & 7)) << 4);
        *(uint4*)((char*)slab + off) = val;
    }
    __syncthreads();

    int m = l & 15, kg = l >> 4;
    int pos0[8];
    #pragma unroll
    for (int nt = 0; nt < 8; ++nt) {
        int pxl = wmN * 128 + nt * 16 + m;         // 0..255 within block
        pos0[nt] = (pxl >> 5) * 34 + (pxl & 31);   // top-left sample (tap 0)
    }

    const f16x8* Wf8 = (const f16x8*)Wf2;
    f32x4 acc[4][8];
    #pragma unroll
    for (int mt = 0; mt < 4; ++mt)
        #pragma unroll
        for (int nt = 0; nt < 8; ++nt)
            acc[mt][nt] = (f32x4){0.f, 0.f, 0.f, 0.f};

    #pragma unroll
    for (int s = 0; s < 18; ++s) {
        int cg = s / 9, r = s % 9;                 // s compile-time (full unroll)
        int dd = (r / 3) * 34 + (r % 3);
        int slotb = (cg * 4 + kg) << 4;
        int ab = (r * 2 + cg) * 32 + ocb * 8 + wmM * 4;

        f16x8 afv[4];
        #pragma unroll
        for (int mt = 0; mt < 4; ++mt)
            afv[mt] = Wf8[(size_t)(ab + mt) * 64 + l];

        #pragma unroll
        for (int nt = 0; nt < 8; ++nt) {
            int pos = pos0[nt] + dd;
            int off = pos * 128 + (slotb ^ ((pos & 7) << 4));
            f16x8 bf = *(const f16x8*)((const char*)slab + off);
            #pragma unroll
            for (int mt = 0; mt < 4; ++mt)
                acc[mt][nt] = __builtin_amdgcn_mfma_f32_16x16x32_f16(afv[mt], bf, acc[mt][nt], 0, 0, 0);
        }
    }

    // epilogue: g[f][oc][px], C frag: row=oc=(kg*4+e), col=px=(m)
    _Float16* gb = g + (size_t)f * 512 * 1024;
    #pragma unroll
    for (int mt = 0; mt < 4; ++mt) {
        int oc0 = (ocb * 8 + wmM * 4 + mt) * 16 + kg * 4;
        #pragma unroll
        for (int nt = 0; nt < 8; ++nt) {
            int px = pxb * 256 + wmN * 128 + nt * 16 + m;
            #pragma unroll
            for (int e = 0; e < 4; ++e)
                gb[(size_t)(oc0 + e) * 1024 + px] = (_Float16)acc[mt][nt][e];
        }
    }
}

// ---------------------------------------------------------------------------
// 6) combine: out[b,o,d,px] = bias[d] + sum_{n,i} w[b,i,n,o] * g[b,i,n*64+d,px]
//    w path: per i, lanes cooperatively load 128 weights (float2/lane), then
//    compile-time __builtin_amdgcn_readlane -> SGPR operand FMAs.
__global__ __launch_bounds__(256) void k_comb(const _Float16* __restrict__ g,
                                              const float* __restrict__ wsm2,
                                              const float* __restrict__ bias_out,
                                              float* __restrict__ out) {
    int d = blockIdx.y, b = blockIdx.z;
    int t = threadIdx.x;
    int px0 = t * 4;
    float acc[16][4];
    #pragma unroll
    for (int o = 0; o < 16; ++o)
        #pragma unroll
        for (int e = 0; e < 4; ++e) acc[o][e] = 0.f;

    for (int i = 0; i < 16; ++i) {
        // lane l holds w[idx=2l], w[idx=2l+1] where idx = n*16+o
        float2 wv = *(const float2*)&wsm2[(size_t)(b * 16 + i) * 128 + 2 * (t & 63)];
        #pragma unroll
        for (int n = 0; n < 8; ++n) {
            const _Float16* gp = g + ((size_t)((b * 16 + i) * 512 + n * 64 + d)) * 1024 + px0;
            f16x4 hv = *(const f16x4*)gp;
            float g0 = (float)hv[0], g1 = (float)hv[1], g2 = (float)hv[2], g3 = (float)hv[3];
            #pragma unroll
            for (int o = 0; o < 16; ++o) {
                int idx = n * 16 + o;
                int src = (idx & 1) ? __float_as_int(wv.y) : __float_as_int(wv.x);
                float w = __int_as_float(__builtin_amdgcn_readlane(src, idx >> 1));
                acc[o][0] += w * g0;
                acc[o][1] += w * g1;
                acc[o][2] += w * g2;
                acc[o][3] += w * g3;
            }
        }
    }
    float bo = bias_out[d];
    #pragma unroll
    for (int o = 0; o < 16; ++o) {
        float4 res = make_float4(acc[o][0] + bo, acc[o][1] + bo, acc[o][2] + bo, acc[o][3] + bo);
        *(float4*)(out + ((size_t)((b * 16 + o) * 64 + d)) * 1024 + px0) = res;
    }
}

// ---------------------------------------------------------------------------
extern "C" void kernel_launch(void* const* d_in, const int* in_sizes, int n_in,
                              void* d_out, int out_size, void* d_ws, size_t ws_size,
                              hipStream_t stream) {
    (void)in_sizes; (void)n_in; (void)out_size;
    const float* v  = (const float*)d_in[0];
    const float* kk = (const float*)d_in[1];
    const float* q  = (const float*)d_in[2];
    const int*   pm = (const int*)d_in[3];
    const float* Wq = (const float*)d_in[4];
    const float* bq = (const float*)d_in[5];
    const float* Wk = (const float*)d_in[6];
    const float* bk = (const float*)d_in[7];
    const float* Wv = (const float*)d_in[8];
    const float* bv = (const float*)d_in[9];
    const float* Wp = (const float*)d_in[10];
    const float* bp = (const float*)d_in[11];
    float* out = (float*)d_out;

    char* ws = (char*)d_ws;
    size_t o_v16t = 0;
    size_t o_g    = o_v16t + (size_t)FR_ * PX_ * DV_ * 2;          // 16 MB
    size_t o_wf2  = o_g    + (size_t)FR_ * 512 * PX_ * 2;          // +128 MB
    size_t o_pq   = o_wf2  + (size_t)9 * 2 * 32 * 64 * 8 * 2;      // +576 KB
    size_t o_pk   = o_pq   + (size_t)128 * 2048 * 4;               // +1 MB
    size_t o_wsm  = o_pk   + (size_t)128 * 2048 * 4;               // +1 MB
    size_t o_bias = o_wsm  + (size_t)NB_ * NH_ * TO_ * TI_ * 4;    // +64 KB
    size_t need   = o_bias + 256;
    if (ws_size < need) return;  // insufficient workspace; validation will flag

    _Float16* v16t = (_Float16*)(ws + o_v16t);
    _Float16* g    = (_Float16*)(ws + o_g);
    _Float16* Wf2  = (_Float16*)(ws + o_wf2);
    float* pq      = (float*)(ws + o_pq);
    float* pk      = (float*)(ws + o_pk);
    float* wsm2    = (float*)(ws + o_wsm);
    float* bias    = (float*)(ws + o_bias);

    k_prep<<<dim3(512), dim3(256), 0, stream>>>(v, v16t);
    k_proj<<<dim3(32, 4, 2), dim3(256), 0, stream>>>(q, kk, Wq, bq, Wk, bk, pq, pk);
    k_scores<<<dim3(64), dim3(256), 0, stream>>>(pq, pk, pm, wsm2);
    k_fold<<<dim3(72), dim3(256), 0, stream>>>(Wp, Wv, Wf2);
    k_foldbias<<<dim3(1), dim3(64), 0, stream>>>(Wp, bv, bp, bias);
    k_conv<<<dim3(4, 4, FR_), dim3(256), 0, stream>>>(v16t, Wf2, g);
    k_comb<<<dim3(1, 64, NB_), dim3(256), 0, stream>>>(g, wsm2, bias, out);
}